// Round 1
// baseline (2206.494 us; speedup 1.0000x reference)
//
#include <hip/hip_runtime.h>

#define BATCH 32
#define SEQ 4096
#define DMODEL 256
#define STATEN 64
#define NCLS 5

// One wave (64 lanes) per (b, d) pair; lane = state index n.
// Folded recurrence: s'_n = A_n*s'_n + fma(P_n, x_t, Q_n), y = sum_n s'_n.
__global__ __launch_bounds__(256) void ssm_scan_kernel(
    const float* __restrict__ x,      // [B, T]
    const float* __restrict__ w_in,   // [D]
    const float* __restrict__ b_in,   // [D]
    const float* __restrict__ A_diag, // [D, N]
    const float* __restrict__ B_in,   // [D, N]
    const float* __restrict__ C_out,  // [D, N]
    const float* __restrict__ D_skip, // [D]
    float* __restrict__ pooled)       // [B, 2D]: [:,0:D]=avg, [:,D:2D]=max
{
    const int gw   = (blockIdx.x * blockDim.x + threadIdx.x) >> 6;
    const int lane = threadIdx.x & 63;
    const int b = gw >> 8;   // 0..31
    const int d = gw & 255;  // 0..255

    const float A  = A_diag[d * STATEN + lane];
    const float CB = B_in[d * STATEN + lane] * C_out[d * STATEN + lane];
    const float wd = w_in[d];
    const float bd = b_in[d];
    const float P  = CB * wd;
    const float Q  = CB * bd;
    const float Dw = D_skip[d] * wd;
    const float Db = D_skip[d] * bd;

    float s   = 0.0f;
    float sum = 0.0f;
    float mx  = -1e30f;

    const float* xb = x + b * SEQ;

    for (int t0 = 0; t0 < SEQ; t0 += 64) {
        // lane l holds x[b, t0+l]; broadcast one per inner step via readlane
        const float xv = xb[t0 + lane];
        #pragma unroll 8
        for (int j = 0; j < 64; ++j) {
            const float xt =
                __int_as_float(__builtin_amdgcn_readlane(__float_as_int(xv), j));
            // state update (2 FMA)
            s = fmaf(A, s, fmaf(P, xt, Q));
            // 64-lane butterfly sum of s' -> y in ALL lanes
            float y = s;
            #pragma unroll
            for (int off = 32; off > 0; off >>= 1)
                y += __shfl_xor(y, off, 64);
            // skip connection + gelu (tanh approx, matches jax.nn.gelu default)
            const float ytot = y + fmaf(xt, Dw, Db);
            const float t2   = ytot * ytot;
            const float zneg = ytot * fmaf(-0.07135481627f, t2, -1.5957691216f);
            const float h    = ytot / (1.0f + __expf(zneg));
            sum += h;
            mx = fmaxf(mx, h);
        }
    }

    // every lane holds identical sum/mx; lane 0 writes
    if (lane == 0) {
        pooled[b * (2 * DMODEL) + d]          = sum * (1.0f / SEQ);
        pooled[b * (2 * DMODEL) + DMODEL + d] = mx;
    }
}

// out[b,c] = pooled[b,:] @ W_head[:,c] + b_head[c]   (tiny: 32x512x5)
__global__ __launch_bounds__(256) void head_kernel(
    const float* __restrict__ pooled,  // [B, 2D]
    const float* __restrict__ W_head,  // [2D, NCLS]
    const float* __restrict__ b_head,  // [NCLS]
    float* __restrict__ out)           // [B, NCLS]
{
    const int tid = blockIdx.x * blockDim.x + threadIdx.x;
    if (tid >= BATCH * NCLS) return;
    const int b = tid / NCLS;
    const int c = tid % NCLS;
    float acc = b_head[c];
    const float* p = pooled + b * (2 * DMODEL);
    for (int k = 0; k < 2 * DMODEL; ++k)
        acc = fmaf(p[k], W_head[k * NCLS + c], acc);
    out[tid] = acc;
}

extern "C" void kernel_launch(void* const* d_in, const int* in_sizes, int n_in,
                              void* d_out, int out_size, void* d_ws, size_t ws_size,
                              hipStream_t stream) {
    const float* x      = (const float*)d_in[0];
    const float* w_in   = (const float*)d_in[1];
    const float* b_in   = (const float*)d_in[2];
    const float* A_diag = (const float*)d_in[3];
    const float* B_in   = (const float*)d_in[4];
    const float* C_out  = (const float*)d_in[5];
    const float* D_skip = (const float*)d_in[6];
    const float* W_head = (const float*)d_in[7];
    const float* b_head = (const float*)d_in[8];
    float* pooled = (float*)d_ws;  // 32*512*4 = 64 KB scratch
    float* out    = (float*)d_out;

    // 8192 waves = 2048 blocks x 4 waves; full single-pass occupancy
    ssm_scan_kernel<<<2048, 256, 0, stream>>>(x, w_in, b_in, A_diag, B_in,
                                              C_out, D_skip, pooled);
    head_kernel<<<1, 256, 0, stream>>>(pooled, W_head, b_head, out);
}

// Round 3
// 314.319 us; speedup vs baseline: 7.0199x; 7.0199x over previous
//
#include <hip/hip_runtime.h>

#define BATCH 32
#define SEQ 4096
#define DMODEL 256
#define NCLS 5

// Wave covers 2 channels (d = 2*pr, 2*pr+1) of one batch row b.
// Lane l: dd = l>>5 (channel within pair), c = l&31; lane owns modes c, c+32.
// Folded recurrence per mode: s' = A*s' + P*x_t + Q  (P=C*B*w_in, Q=C*B*b_in),
// y(t) = sum_modes s' + Dw*x_t + Db,  h = gelu(y).
// Chunk of 32 t: stage partials (s_c + s_{c+32}) to LDS rows, barrier,
// lane c reduces row c (time t0+j0+c), gelu, pool accumulate.
__global__ __launch_bounds__(256) void ssm_scan_kernel(
    const float* __restrict__ x,      // [B, T]
    const float* __restrict__ w_in,   // [D]
    const float* __restrict__ b_in,   // [D]
    const float* __restrict__ A_diag, // [D, 64]
    const float* __restrict__ B_in,   // [D, 64]
    const float* __restrict__ C_out,  // [D, 64]
    const float* __restrict__ D_skip, // [D]
    float* __restrict__ pooled)       // [B, 2D]
{
    __shared__ float tile[4][2112];   // per wave: 2 ch * 32 rows * 33 (pad)

    const int wid  = threadIdx.x >> 6;
    const int lane = threadIdx.x & 63;
    const int gw   = blockIdx.x * 4 + wid;   // 0..4095
    const int b    = gw >> 7;                // 0..31
    const int pr   = gw & 127;               // channel pair index
    const int dd   = lane >> 5;
    const int c    = lane & 31;
    const int d    = 2 * pr + dd;

    const float A0  = A_diag[d * 64 + c];
    const float A1  = A_diag[d * 64 + c + 32];
    const float wd  = w_in[d];
    const float bd  = b_in[d];
    const float CB0 = B_in[d * 64 + c]      * C_out[d * 64 + c];
    const float CB1 = B_in[d * 64 + c + 32] * C_out[d * 64 + c + 32];
    const float P0  = CB0 * wd, Q0 = CB0 * bd;
    const float P1  = CB1 * wd, Q1 = CB1 * bd;
    const float Dw  = D_skip[d] * wd;
    const float Db  = D_skip[d] * bd;

    float s0 = 0.0f, s1 = 0.0f;
    float sum = 0.0f;
    float mx  = -1e30f;

    const float* xb = x + b * SEQ;
    float*       tw = &tile[wid][dd * 1056 + c];      // write: column c, row j
    const float* tr = &tile[wid][dd * 1056 + c * 33]; // read: row c

    for (int t0 = 0; t0 < SEQ; t0 += 64) {
        const float xv = xb[t0 + lane];   // 64 timesteps, coalesced

        #pragma unroll
        for (int ch = 0; ch < 2; ++ch) {
            const int j0 = ch * 32;
            // ---- t-phase: 32 steps, store partial mode-sums to LDS rows ----
            #pragma unroll
            for (int j = 0; j < 32; ++j) {
                const float xt = __int_as_float(
                    __builtin_amdgcn_readlane(__float_as_int(xv), j0 + j));
                s0 = fmaf(A0, s0, fmaf(P0, xt, Q0));
                s1 = fmaf(A1, s1, fmaf(P1, xt, Q1));
                tw[j * 33] = s0 + s1;     // bank (j+c)%32: 2-way = free
            }
            __syncthreads();              // LDS transpose barrier (write->read)
            // ---- reduce phase: lane sums its row (t = t0+j0+c) ----
            float ya = 0.0f, yb2 = 0.0f;
            #pragma unroll
            for (int i = 0; i < 32; i += 2) {
                ya  += tr[i];
                yb2 += tr[i + 1];
            }
            const float xtr = xb[t0 + j0 + c];   // x at this lane's row (L1 hit)
            const float yt  = (ya + yb2) + fmaf(xtr, Dw, Db);
            // gelu (tanh approx == x * sigmoid(1.59577x + 0.0713548x^3))
            const float y2 = yt * yt;
            const float zn = yt * fmaf(-0.07135481627f, y2, -1.5957691216f);
            const float h  = yt / (1.0f + __expf(zn));
            sum += h;
            mx = fmaxf(mx, h);
            __syncthreads();              // read->next write
        }
    }

    // combine within each 32-lane half (offsets <32 never cross halves)
    #pragma unroll
    for (int off = 16; off > 0; off >>= 1) {
        sum += __shfl_xor(sum, off, 64);
        mx   = fmaxf(mx, __shfl_xor(mx, off, 64));
    }
    if (c == 0) {   // lane 0 -> d (pair ch 0), lane 32 -> d (pair ch 1)
        pooled[b * (2 * DMODEL) + d]          = sum * (1.0f / SEQ);
        pooled[b * (2 * DMODEL) + DMODEL + d] = mx;
    }
}

// out[b,c] = pooled[b,:] @ W_head[:,c] + b_head[c]   (tiny: 32x512x5)
__global__ __launch_bounds__(256) void head_kernel(
    const float* __restrict__ pooled,
    const float* __restrict__ W_head,
    const float* __restrict__ b_head,
    float* __restrict__ out)
{
    const int tid = blockIdx.x * blockDim.x + threadIdx.x;
    if (tid >= BATCH * NCLS) return;
    const int b = tid / NCLS;
    const int c = tid % NCLS;
    float acc = b_head[c];
    const float* p = pooled + b * (2 * DMODEL);
    for (int k = 0; k < 2 * DMODEL; ++k)
        acc = fmaf(p[k], W_head[k * NCLS + c], acc);
    out[tid] = acc;
}

extern "C" void kernel_launch(void* const* d_in, const int* in_sizes, int n_in,
                              void* d_out, int out_size, void* d_ws, size_t ws_size,
                              hipStream_t stream) {
    const float* x      = (const float*)d_in[0];
    const float* w_in   = (const float*)d_in[1];
    const float* b_in   = (const float*)d_in[2];
    const float* A_diag = (const float*)d_in[3];
    const float* B_in   = (const float*)d_in[4];
    const float* C_out  = (const float*)d_in[5];
    const float* D_skip = (const float*)d_in[6];
    const float* W_head = (const float*)d_in[7];
    const float* b_head = (const float*)d_in[8];
    float* pooled = (float*)d_ws;   // 32*512*4 = 64 KB scratch
    float* out    = (float*)d_out;

    // 4096 waves (2 channels each) = 1024 blocks; ~4 blocks/CU, single pass
    ssm_scan_kernel<<<1024, 256, 0, stream>>>(x, w_in, b_in, A_diag, B_in,
                                              C_out, D_skip, pooled);
    head_kernel<<<1, 256, 0, stream>>>(pooled, W_head, b_head, out);
}